// Round 13
// baseline (81.529 us; speedup 1.0000x reference)
//
#include <hip/hip_runtime.h>
#include <hip/hip_bf16.h>

#define BATCH 16
#define NNODE 2048
#define NEDGE 65536
#define DIN   256
#define DOUT  256
#define KDIM  512   // 2*DIN
#define SUB   16            // sub-blocks per batch
#define ESUB  (NEDGE/SUB)   // 4096 edges per sub-block

typedef __attribute__((ext_vector_type(8))) short short8;
typedef __attribute__((ext_vector_type(4))) float f32x4;

__device__ __forceinline__ ushort f2bf(float f) {
    union { float f; unsigned u; } v; v.f = f;
    unsigned u = v.u;
    unsigned r = (u + 0x7fffu + ((u >> 16) & 1u)) >> 16;  // RNE
    return (ushort)r;
}

// int8 feature quantization, scale 16
__device__ __forceinline__ int q8(float x) {
    float c = fminf(fmaxf(x * 16.0f, -127.0f), 127.0f);
    return (int)rintf(c);
}

// fp8 e4m3fn encode (manual fallback, RNE)
__device__ __forceinline__ unsigned f2e4m3(float x) {
    unsigned u = __float_as_uint(x);
    unsigned s = (u >> 24) & 0x80u;
    float ax = __uint_as_float(u & 0x7FFFFFFFu);
    if (ax >= 448.0f) return s | 0x7Eu;
    if (ax < 0.0009765625f) return s;            // < 2^-10 -> 0
    if (ax < 0.015625f) {                        // subnormal
        int q = (int)rintf(ax * 512.0f);
        return s | (unsigned)q;
    }
    unsigned au = __float_as_uint(ax);
    int e = (int)((au >> 23) & 0xFF) - 127;
    unsigned m = au & 0x7FFFFFu;
    unsigned keep = m >> 20;
    unsigned rest = m & 0xFFFFFu;
    keep += (rest > 0x80000u) || (rest == 0x80000u && (keep & 1u));
    unsigned val = ((unsigned)(e + 7) << 3) + keep;
    if (val > 0x7Eu) val = 0x7Eu;
    return s | val;
}
template <bool HI>
__device__ __forceinline__ unsigned pk2_fp8(float a, float b, unsigned old) {
#if __has_builtin(__builtin_amdgcn_cvt_pk_fp8_f32)
    return (unsigned)__builtin_amdgcn_cvt_pk_fp8_f32(a, b, (int)old, HI);
#else
    unsigned p = f2e4m3(a) | (f2e4m3(b) << 8);
    return HI ? ((old & 0xFFFFu) | (p << 16)) : ((old & 0xFFFF0000u) | p);
#endif
}

#define ASYNC_COPY16(gsrc, ldst) \
    __builtin_amdgcn_global_load_lds((const __attribute__((address_space(1))) void*)(gsrc), \
                                     (__attribute__((address_space(3))) void*)(ldst), 16, 0, 0)

// ---------------------------------------------------------------------------
// prep (4416 blocks x 256 thr):
//   [0,256):     partial histograms (b = bid&15, sub = bid>>4)
//   [256,4352):  convert X fp32 -> bf16 (GEMM X-half) + int8 (gather)
//   [4352,4416): convert W: k<256 -> bf16 [col][512]; k>=256 -> fp8 e4m3
//                pre-arranged [kt][kq][col][8] for linear LDS staging.
// ---------------------------------------------------------------------------
__global__ __launch_bounds__(256) void prep_kernel(
        const float* __restrict__ X, const float* __restrict__ W,
        const int* __restrict__ E,
        int* __restrict__ partial,
        ushort* __restrict__ Xbf, unsigned char* __restrict__ Xi8,
        ushort* __restrict__ Wbf, unsigned char* __restrict__ Wf8s) {
    int bid = blockIdx.x;
    int t = threadIdx.x;
    if (bid < 256) {
        __shared__ int hist[NNODE];
        int b = bid & 15, sub = bid >> 4;
#pragma unroll
        for (int j = 0; j < 8; ++j) hist[t + j * 256] = 0;
        __syncthreads();
        const int4* dsts = reinterpret_cast<const int4*>(
            E + (size_t)b * 2 * NEDGE + NEDGE + sub * ESUB);
#pragma unroll
        for (int j = 0; j < 4; ++j) {
            int4 d = dsts[j * 256 + t];
            atomicAdd(&hist[d.x], 1);
            atomicAdd(&hist[d.y], 1);
            atomicAdd(&hist[d.z], 1);
            atomicAdd(&hist[d.w], 1);
        }
        __syncthreads();
        int* pb = partial + ((size_t)b * SUB + sub) * NNODE;
#pragma unroll
        for (int j = 0; j < 8; ++j) pb[t + j * 256] = hist[t + j * 256];
    } else if (bid < 4352) {
        size_t i = (size_t)(bid - 256) * 256 + t;
        const float4* p = reinterpret_cast<const float4*>(X + i * 8);
        float4 u = p[0], v = p[1];
        ushort4 o0 = { f2bf(u.x), f2bf(u.y), f2bf(u.z), f2bf(u.w) };
        ushort4 o1 = { f2bf(v.x), f2bf(v.y), f2bf(v.z), f2bf(v.w) };
        *reinterpret_cast<ushort4*>(Xbf + i * 8)     = o0;
        *reinterpret_cast<ushort4*>(Xbf + i * 8 + 4) = o1;
        unsigned q0 = (q8(u.x) & 255) | ((q8(u.y) & 255) << 8) |
                      ((q8(u.z) & 255) << 16) | ((unsigned)(q8(u.w) & 255) << 24);
        unsigned q1 = (q8(v.x) & 255) | ((q8(v.y) & 255) << 8) |
                      ((q8(v.z) & 255) << 16) | ((unsigned)(q8(v.w) & 255) << 24);
        uint2 q = { q0, q1 };
        *reinterpret_cast<uint2*>(Xi8 + i * 8) = q;
    } else {
        int i = (bid - 4352) * 256 + t;            // 0..16383
        int col = i >> 6;
        int k = (i & 63) * 8;
        const float4* p = reinterpret_cast<const float4*>(W + (size_t)col * KDIM + k);
        float4 u = p[0], v = p[1];
        if (k < DIN) {
            ushort4 o0 = { f2bf(u.x), f2bf(u.y), f2bf(u.z), f2bf(u.w) };
            ushort4 o1 = { f2bf(v.x), f2bf(v.y), f2bf(v.z), f2bf(v.w) };
            *reinterpret_cast<ushort4*>(Wbf + (size_t)col * KDIM + k)     = o0;
            *reinterpret_cast<ushort4*>(Wbf + (size_t)col * KDIM + k + 4) = o1;
        } else {
            unsigned w0 = pk2_fp8<false>(u.x, u.y, 0u);
            w0 = pk2_fp8<true>(u.z, u.w, w0);
            unsigned w1 = pk2_fp8<false>(v.x, v.y, 0u);
            w1 = pk2_fp8<true>(v.z, v.w, w1);
            int kk = k - DIN;
            int kt = kk >> 5, kq = (kk >> 3) & 3;
            uint2 qv = { w0, w1 };
            *reinterpret_cast<uint2*>(Wf8s + (size_t)kt * 8192 + kq * 2048 + col * 8) = qv;
        }
    }
}

// ---------------------------------------------------------------------------
// fillscan (256 blocks x 256 thr): per-(batch,sub) scan of partials + scatter.
// cursor ends as START offsets; counts written by sub==0.
// ---------------------------------------------------------------------------
__global__ __launch_bounds__(256) void fillscan_kernel(
        const int* __restrict__ E,
        const int* __restrict__ partial,
        int* __restrict__ counts, int* __restrict__ cursor,
        int* __restrict__ srcIdx) {
    __shared__ int cur[NNODE];
    __shared__ int tsum[256];
    int bid = blockIdx.x;
    int t = threadIdx.x;
    int b = bid & 15, sub = bid >> 4;
    const int* pb = partial + (size_t)b * SUB * NNODE;

    int tot[8] = {}, pre[8] = {};
    for (int k = 0; k < SUB; ++k) {
        const int4* p = reinterpret_cast<const int4*>(pb + k * NNODE + t * 8);
        int4 a = p[0], c = p[1];
        if (k < sub) {
            pre[0] += a.x; pre[1] += a.y; pre[2] += a.z; pre[3] += a.w;
            pre[4] += c.x; pre[5] += c.y; pre[6] += c.z; pre[7] += c.w;
        }
        tot[0] += a.x; tot[1] += a.y; tot[2] += a.z; tot[3] += a.w;
        tot[4] += c.x; tot[5] += c.y; tot[6] += c.z; tot[7] += c.w;
    }
    int s = 0;
#pragma unroll
    for (int j = 0; j < 8; ++j) s += tot[j];
    tsum[t] = s;
    __syncthreads();
    for (int off = 1; off < 256; off <<= 1) {
        int v = (t >= off) ? tsum[t - off] : 0;
        __syncthreads();
        tsum[t] += v;
        __syncthreads();
    }
    int run = (t == 0) ? 0 : tsum[t - 1];
    bool writer = (sub == 0);
    int base = b * NNODE + t * 8;
#pragma unroll
    for (int j = 0; j < 8; ++j) {
        cur[t * 8 + j] = run + pre[j];
        if (writer) { counts[base + j] = tot[j]; cursor[base + j] = run; }
        run += tot[j];
    }
    __syncthreads();

    const int* eb = E + (size_t)b * 2 * NEDGE;
    const int4* srcs = reinterpret_cast<const int4*>(eb + sub * ESUB);
    const int4* dsts = reinterpret_cast<const int4*>(eb + NEDGE + sub * ESUB);
    int* sb = srcIdx + (size_t)b * NEDGE;
#pragma unroll
    for (int j = 0; j < 4; ++j) {
        int4 sv = srcs[j * 256 + t];
        int4 dv = dsts[j * 256 + t];
        sb[atomicAdd(&cur[dv.x], 1)] = sv.x;
        sb[atomicAdd(&cur[dv.y], 1)] = sv.y;
        sb[atomicAdd(&cur[dv.z], 1)] = sv.z;
        sb[atomicAdd(&cur[dv.w], 1)] = sv.w;
    }
}

// ---------------------------------------------------------------------------
// FUSED aggregate + GEMM. 256 blocks x 512 thr; tile 128 rows x 256 cols.
// Phase A: 8 waves x 16 nodes: SWAR int8 gather -> mean -> fp8 into LDS Gq
//   (chunk swizzle slot = l16 ^ ((r>>1)&7) + word-pair rotate by r&1).
// Phase B: 16 K-steps: t<8 bf16 MFMA (Xbf/Wbf staged, global_load_lds,
//   counted vmcnt); t>=8 fp8 MFMA, A straight from Gq, B fp8 staged linearly
//   (aliasing the bf16 B buffers phase-disjointly).
// LDS = 16 + 32 + 32 = 80 KB -> 2 blocks/CU.
// ---------------------------------------------------------------------------
__global__ __launch_bounds__(512, 4) void gemm_fused(
        const ushort* __restrict__ Xbf,
        const unsigned char* __restrict__ Xi8,
        const ushort* __restrict__ Wbf,
        const unsigned char* __restrict__ Wf8s,
        const int* __restrict__ srcIdx,
        const int* __restrict__ cursor,
        const int* __restrict__ counts,
        const float* __restrict__ bias,
        float* __restrict__ out) {
    __shared__ ushort As[2][128 * 32];     // 16 KB
    __shared__ ushort Bs[2][256 * 32];     // 32 KB (fp8 tiles alias low 8 KB)
    __shared__ uint4  GqV[2048];           // 32 KB fp8 G

    const int tid = threadIdx.x;
    const int wid = tid >> 6, lane = tid & 63;
    const int wm = wid >> 2, wn = wid & 3;         // 2 x 4 wave grid

    int orig = blockIdx.x;                          // 256 blocks
    int logical = (orig & 7) * 32 + (orig >> 3);    // XCD-chunked bijective
    const int rowBase = logical * 128;
    const int b = rowBase >> 11;

    f32x4 acc[4][4] = {};

    // staging geometry
    const int r0 = wid * 16 + (lane >> 2);          // 0..127
    const int lk = (((lane & 3) ^ ((lane >> 3) & 3)) * 8);
    const ushort* Arow = Xbf + (size_t)rowBase * DIN;

#define STAGE_X(k0, buf) do {                                                  \
        ASYNC_COPY16(Arow + (size_t)r0 * DIN + (k0) + lk,         &As[buf][wid * 512]);        \
        ASYNC_COPY16(Wbf + (size_t)r0 * KDIM + (k0) + lk,         &Bs[buf][wid * 512]);        \
        ASYNC_COPY16(Wbf + (size_t)(r0 + 128) * KDIM + (k0) + lk, &Bs[buf][4096 + wid * 512]); \
    } while (0)
#define STAGE_G(kt, fbuf) \
        ASYNC_COPY16(Wf8s + (size_t)(kt) * 8192 + (size_t)(wid * 64 + lane) * 16, \
                     &Bs[fbuf][wid * 512])

    STAGE_X(0, 0);   // tile 0 in flight during phase A

    // ---------------- Phase A: aggregate 128 rows -> Gq (fp8) ---------------
    {
        const int q = lane >> 4, l16 = lane & 15;
        const int f0 = l16 * 16;
        const unsigned char* xb = Xi8 + (size_t)b * NNODE * DIN;
#define M16 0x00FF00FFu
#define ACC16(v) do {                                                         \
        unsigned w0 = (v).x ^ 0x80808080u, w1 = (v).y ^ 0x80808080u;          \
        unsigned w2 = (v).z ^ 0x80808080u, w3 = (v).w ^ 0x80808080u;          \
        a0 += w0 & M16;  a1 += (w0 >> 8) & M16;                               \
        a2 += w1 & M16;  a3 += (w1 >> 8) & M16;                               \
        a4 += w2 & M16;  a5 += (w2 >> 8) & M16;                               \
        a6 += w3 & M16;  a7 += (w3 >> 8) & M16;                               \
    } while (0)
        for (int nn = 0; nn < 16; ++nn) {
            int r = wid * 16 + nn;
            int node = rowBase + r;
            int deg = counts[node];
            int start = cursor[node];
            const int* sidx = srcIdx + (size_t)b * NEDGE + start;
            unsigned a0 = 0, a1 = 0, a2 = 0, a3 = 0, a4 = 0, a5 = 0, a6 = 0, a7 = 0;
            int i = 0;
            for (; i + 16 <= deg; i += 16) {
                int s0 = sidx[i + q], s1 = sidx[i + 4 + q];
                int s2 = sidx[i + 8 + q], s3 = sidx[i + 12 + q];
                uint4 v0 = *reinterpret_cast<const uint4*>(xb + (size_t)s0 * DIN + f0);
                uint4 v1 = *reinterpret_cast<const uint4*>(xb + (size_t)s1 * DIN + f0);
                uint4 v2 = *reinterpret_cast<const uint4*>(xb + (size_t)s2 * DIN + f0);
                uint4 v3 = *reinterpret_cast<const uint4*>(xb + (size_t)s3 * DIN + f0);
                ACC16(v0); ACC16(v1); ACC16(v2); ACC16(v3);
            }
            for (; i < deg; i += 4) {
                int e = i + q;
                uint4 v = { 0x80808080u, 0x80808080u, 0x80808080u, 0x80808080u };
                if (e < deg)
                    v = *reinterpret_cast<const uint4*>(xb + (size_t)sidx[e] * DIN + f0);
                ACC16(v);
            }
            a0 += (unsigned)__shfl_xor((int)a0, 16, 64); a0 += (unsigned)__shfl_xor((int)a0, 32, 64);
            a1 += (unsigned)__shfl_xor((int)a1, 16, 64); a1 += (unsigned)__shfl_xor((int)a1, 32, 64);
            a2 += (unsigned)__shfl_xor((int)a2, 16, 64); a2 += (unsigned)__shfl_xor((int)a2, 32, 64);
            a3 += (unsigned)__shfl_xor((int)a3, 16, 64); a3 += (unsigned)__shfl_xor((int)a3, 32, 64);
            a4 += (unsigned)__shfl_xor((int)a4, 16, 64); a4 += (unsigned)__shfl_xor((int)a4, 32, 64);
            a5 += (unsigned)__shfl_xor((int)a5, 16, 64); a5 += (unsigned)__shfl_xor((int)a5, 32, 64);
            a6 += (unsigned)__shfl_xor((int)a6, 16, 64); a6 += (unsigned)__shfl_xor((int)a6, 32, 64);
            a7 += (unsigned)__shfl_xor((int)a7, 16, 64); a7 += (unsigned)__shfl_xor((int)a7, 32, 64);
            if (q == 0) {
                float sc = 1.0f / (16.0f * (float)max(deg, 1));
                float bs = 128.0f * (float)deg;
                float f[16];
                f[ 0] = ((float)(int)(a0 & 0xFFFFu) - bs) * sc;
                f[ 2] = ((float)(int)(a0 >> 16)     - bs) * sc;
                f[ 1] = ((float)(int)(a1 & 0xFFFFu) - bs) * sc;
                f[ 3] = ((float)(int)(a1 >> 16)     - bs) * sc;
                f[ 4] = ((float)(int)(a2 & 0xFFFFu) - bs) * sc;
                f[ 6] = ((float)(int)(a2 >> 16)     - bs) * sc;
                f[ 5] = ((float)(int)(a3 & 0xFFFFu) - bs) * sc;
                f[ 7] = ((float)(int)(a3 >> 16)     - bs) * sc;
                f[ 8] = ((float)(int)(a4 & 0xFFFFu) - bs) * sc;
                f[10] = ((float)(int)(a4 >> 16)     - bs) * sc;
                f[ 9] = ((float)(int)(a5 & 0xFFFFu) - bs) * sc;
                f[11] = ((float)(int)(a5 >> 16)     - bs) * sc;
                f[12] = ((float)(int)(a6 & 0xFFFFu) - bs) * sc;
                f[14] = ((float)(int)(a6 >> 16)     - bs) * sc;
                f[13] = ((float)(int)(a7 & 0xFFFFu) - bs) * sc;
                f[15] = ((float)(int)(a7 >> 16)     - bs) * sc;
                unsigned wds[4];
#pragma unroll
                for (int w = 0; w < 4; ++w) {
                    unsigned t0 = pk2_fp8<false>(f[4 * w], f[4 * w + 1], 0u);
                    wds[w] = pk2_fp8<true>(f[4 * w + 2], f[4 * w + 3], t0);
                }
                int slot = l16 ^ ((r >> 1) & 7);
                uint4 val;
                if (r & 1) { val.x = wds[2]; val.y = wds[3]; val.z = wds[0]; val.w = wds[1]; }
                else       { val.x = wds[0]; val.y = wds[1]; val.z = wds[2]; val.w = wds[3]; }
                GqV[r * 16 + slot] = val;
            }
        }
#undef ACC16
#undef M16
    }
    __syncthreads();

    // ---------------- Phase B: K-loop -----------------
    const int fl = lane & 15;
    const int kq = lane >> 4;
    const int fc = (kq ^ ((fl >> 1) & 3)) * 8;     // bf16 fragment chunk (ushorts)
    const long* GqL = reinterpret_cast<const long*>(GqV);

    for (int t = 0; t < 16; ++t) {
        if (t < 7) {
            STAGE_X((t + 1) * 32, (t + 1) & 1);
            asm volatile("s_waitcnt vmcnt(3)" ::: "memory");
        } else if (t < 15) {
            STAGE_G(t - 7, (t - 7) & 1);
            asm volatile("s_waitcnt vmcnt(1)" ::: "memory");
        } else {
            asm volatile("s_waitcnt vmcnt(0)" ::: "memory");
        }
        __builtin_amdgcn_s_barrier();

        if (t < 8) {
            const int bufx = t & 1;
            short8 a[4], bb[4];
#pragma unroll
            for (int m = 0; m < 4; ++m)
                a[m] = *reinterpret_cast<const short8*>(
                    &As[bufx][(wm * 64 + m * 16 + fl) * 32 + fc]);
#pragma unroll
            for (int n = 0; n < 4; ++n)
                bb[n] = *reinterpret_cast<const short8*>(
                    &Bs[bufx][(wn * 64 + n * 16 + fl) * 32 + fc]);
#pragma unroll
            for (int m = 0; m < 4; ++m)
#pragma unroll
                for (int n = 0; n < 4; ++n)
                    acc[m][n] = __builtin_amdgcn_mfma_f32_16x16x32_bf16(
                        a[m], bb[n], acc[m][n], 0, 0, 0);
        } else {
            const int kt = t - 8;
            const unsigned char* Bf8 =
                reinterpret_cast<const unsigned char*>(&Bs[kt & 1][0]);
            long ag[4], bg[4];
#pragma unroll
            for (int m = 0; m < 4; ++m) {
                int r = wm * 64 + m * 16 + fl;
                ag[m] = GqL[r * 32 + ((kt * 4 + kq) ^ (r & 15))];
            }
#pragma unroll
            for (int n = 0; n < 4; ++n) {
                int c = wn * 64 + n * 16 + fl;
                bg[n] = *reinterpret_cast<const long*>(Bf8 + kq * 2048 + c * 8);
            }
#pragma unroll
            for (int m = 0; m < 4; ++m)
#pragma unroll
                for (int n = 0; n < 4; ++n)
                    acc[m][n] = __builtin_amdgcn_mfma_f32_16x16x32_fp8_fp8(
                        ag[m], bg[n], acc[m][n], 0, 0, 0);
        }
        __builtin_amdgcn_s_barrier();
    }
#undef STAGE_X
#undef STAGE_G

    // epilogue: C/D layout col=lane&15, row=(lane>>4)*4+reg
    const int cl = lane & 15, rq = lane >> 4;
#pragma unroll
    for (int n = 0; n < 4; ++n) {
        int col = wn * 64 + n * 16 + cl;
        float bv = bias[col];
#pragma unroll
        for (int m = 0; m < 4; ++m) {
            int r0o = rowBase + wm * 64 + m * 16 + rq * 4;
#pragma unroll
            for (int j = 0; j < 4; ++j)
                out[(size_t)(r0o + j) * DOUT + col] = acc[m][n][j] + bv;
        }
    }
}

// ---------------------------------------------------------------------------
extern "C" void kernel_launch(void* const* d_in, const int* in_sizes, int n_in,
                              void* d_out, int out_size, void* d_ws, size_t ws_size,
                              hipStream_t stream) {
    const float* X    = (const float*)d_in[0];   // (B, N, DIN)
    const int*   E    = (const int*)d_in[1];     // (B, 2, NEDGE) int32
    const float* W    = (const float*)d_in[2];   // (DOUT, KDIM)
    const float* bias = (const float*)d_in[3];   // (DOUT,)
    float* out = (float*)d_out;                  // (B, N, DOUT)

    char* ws = (char*)d_ws;
    ushort* Xbf  = (ushort*)ws;                                       // 16.78 MB
    unsigned char* Xi8 = (unsigned char*)(Xbf + (size_t)BATCH * NNODE * DIN); // 8.39 MB
    ushort* Wbf  = (ushort*)(Xi8 + (size_t)BATCH * NNODE * DIN);      // 512 KB
    unsigned char* Wf8s = (unsigned char*)(Wbf + (size_t)DOUT * KDIM);// 64 KB
    int* counts  = (int*)(Wf8s + 8 * 8192);                           // 128 KB
    int* cursor  = counts + BATCH * NNODE;                            // 128 KB
    int* srcIdx  = cursor + BATCH * NNODE;                            // 4 MB
    int* partial = srcIdx + (size_t)BATCH * NEDGE;                    // 2 MB

    // partial hists (256) + convert X bf16+i8 (4096) + convert W bf16/fp8 (64)
    prep_kernel<<<4416, 256, 0, stream>>>(X, W, E, partial, Xbf, Xi8, Wbf, Wf8s);

    fillscan_kernel<<<256, 256, 0, stream>>>(E, partial, counts, cursor, srcIdx);

    gemm_fused<<<256, 512, 0, stream>>>(Xbf, Xi8, Wbf, Wf8s,
                                        srcIdx, cursor, counts, bias, out);
}

// Round 14
// 67.349 us; speedup vs baseline: 1.2105x; 1.2105x over previous
//
#include <hip/hip_runtime.h>
#include <hip/hip_bf16.h>

#define BATCH 16
#define NNODE 2048
#define NEDGE 65536
#define DIN   256
#define DOUT  256
#define KDIM  512   // 2*DIN
#define SUB   16            // sub-blocks per batch
#define ESUB  (NEDGE/SUB)   // 4096 edges per sub-block

typedef __attribute__((ext_vector_type(8))) short short8;
typedef __attribute__((ext_vector_type(4))) float f32x4;

__device__ __forceinline__ ushort f2bf(float f) {
    union { float f; unsigned u; } v; v.f = f;
    unsigned u = v.u;
    unsigned r = (u + 0x7fffu + ((u >> 16) & 1u)) >> 16;  // RNE
    return (ushort)r;
}

// int8 feature quantization, scale 16
__device__ __forceinline__ int q8(float x) {
    float c = fminf(fmaxf(x * 16.0f, -127.0f), 127.0f);
    return (int)rintf(c);
}

// fp8 e4m3fn encode (manual fallback, RNE)
__device__ __forceinline__ unsigned f2e4m3(float x) {
    unsigned u = __float_as_uint(x);
    unsigned s = (u >> 24) & 0x80u;
    float ax = __uint_as_float(u & 0x7FFFFFFFu);
    if (ax >= 448.0f) return s | 0x7Eu;
    if (ax < 0.0009765625f) return s;
    if (ax < 0.015625f) {
        int q = (int)rintf(ax * 512.0f);
        return s | (unsigned)q;
    }
    unsigned au = __float_as_uint(ax);
    int e = (int)((au >> 23) & 0xFF) - 127;
    unsigned m = au & 0x7FFFFFu;
    unsigned keep = m >> 20;
    unsigned rest = m & 0xFFFFFu;
    keep += (rest > 0x80000u) || (rest == 0x80000u && (keep & 1u));
    unsigned val = ((unsigned)(e + 7) << 3) + keep;
    if (val > 0x7Eu) val = 0x7Eu;
    return s | val;
}
template <bool HI>
__device__ __forceinline__ unsigned pk2_fp8(float a, float b, unsigned old) {
#if __has_builtin(__builtin_amdgcn_cvt_pk_fp8_f32)
    return (unsigned)__builtin_amdgcn_cvt_pk_fp8_f32(a, b, (int)old, HI);
#else
    unsigned p = f2e4m3(a) | (f2e4m3(b) << 8);
    return HI ? ((old & 0xFFFFu) | (p << 16)) : ((old & 0xFFFF0000u) | p);
#endif
}

#define ASYNC_COPY16(gsrc, ldst) \
    __builtin_amdgcn_global_load_lds((const __attribute__((address_space(1))) void*)(gsrc), \
                                     (__attribute__((address_space(3))) void*)(ldst), 16, 0, 0)

// ---------------------------------------------------------------------------
// prep (4416 blocks x 256 thr):
//   [0,256):     partial histograms (b = bid&15, sub = bid>>4)
//   [256,4352):  convert X fp32 -> bf16 (GEMM X-half) + int8 (gather)
//   [4352,4416): convert W: k<256 -> bf16 [col][512]; k>=256 -> fp8 e4m3
//                pre-arranged [kt][kq][col][8] for linear LDS staging.
// ---------------------------------------------------------------------------
__global__ __launch_bounds__(256) void prep_kernel(
        const float* __restrict__ X, const float* __restrict__ W,
        const int* __restrict__ E,
        int* __restrict__ partial,
        ushort* __restrict__ Xbf, unsigned char* __restrict__ Xi8,
        ushort* __restrict__ Wbf, unsigned char* __restrict__ Wf8s) {
    int bid = blockIdx.x;
    int t = threadIdx.x;
    if (bid < 256) {
        __shared__ int hist[NNODE];
        int b = bid & 15, sub = bid >> 4;
#pragma unroll
        for (int j = 0; j < 8; ++j) hist[t + j * 256] = 0;
        __syncthreads();
        const int4* dsts = reinterpret_cast<const int4*>(
            E + (size_t)b * 2 * NEDGE + NEDGE + sub * ESUB);
#pragma unroll
        for (int j = 0; j < 4; ++j) {
            int4 d = dsts[j * 256 + t];
            atomicAdd(&hist[d.x], 1);
            atomicAdd(&hist[d.y], 1);
            atomicAdd(&hist[d.z], 1);
            atomicAdd(&hist[d.w], 1);
        }
        __syncthreads();
        int* pb = partial + ((size_t)b * SUB + sub) * NNODE;
#pragma unroll
        for (int j = 0; j < 8; ++j) pb[t + j * 256] = hist[t + j * 256];
    } else if (bid < 4352) {
        size_t i = (size_t)(bid - 256) * 256 + t;
        const float4* p = reinterpret_cast<const float4*>(X + i * 8);
        float4 u = p[0], v = p[1];
        ushort4 o0 = { f2bf(u.x), f2bf(u.y), f2bf(u.z), f2bf(u.w) };
        ushort4 o1 = { f2bf(v.x), f2bf(v.y), f2bf(v.z), f2bf(v.w) };
        *reinterpret_cast<ushort4*>(Xbf + i * 8)     = o0;
        *reinterpret_cast<ushort4*>(Xbf + i * 8 + 4) = o1;
        unsigned q0 = (q8(u.x) & 255) | ((q8(u.y) & 255) << 8) |
                      ((q8(u.z) & 255) << 16) | ((unsigned)(q8(u.w) & 255) << 24);
        unsigned q1 = (q8(v.x) & 255) | ((q8(v.y) & 255) << 8) |
                      ((q8(v.z) & 255) << 16) | ((unsigned)(q8(v.w) & 255) << 24);
        uint2 q = { q0, q1 };
        *reinterpret_cast<uint2*>(Xi8 + i * 8) = q;
    } else {
        int i = (bid - 4352) * 256 + t;            // 0..16383
        int col = i >> 6;
        int k = (i & 63) * 8;
        const float4* p = reinterpret_cast<const float4*>(W + (size_t)col * KDIM + k);
        float4 u = p[0], v = p[1];
        if (k < DIN) {
            ushort4 o0 = { f2bf(u.x), f2bf(u.y), f2bf(u.z), f2bf(u.w) };
            ushort4 o1 = { f2bf(v.x), f2bf(v.y), f2bf(v.z), f2bf(v.w) };
            *reinterpret_cast<ushort4*>(Wbf + (size_t)col * KDIM + k)     = o0;
            *reinterpret_cast<ushort4*>(Wbf + (size_t)col * KDIM + k + 4) = o1;
        } else {
            unsigned w0 = pk2_fp8<false>(u.x, u.y, 0u);
            w0 = pk2_fp8<true>(u.z, u.w, w0);
            unsigned w1 = pk2_fp8<false>(v.x, v.y, 0u);
            w1 = pk2_fp8<true>(v.z, v.w, w1);
            int kk = k - DIN;
            int kt = kk >> 5, kq = (kk >> 3) & 3;
            uint2 qv = { w0, w1 };
            *reinterpret_cast<uint2*>(Wf8s + (size_t)kt * 8192 + kq * 2048 + col * 8) = qv;
        }
    }
}

// ---------------------------------------------------------------------------
// fillscan (256 blocks x 256 thr): per-(batch,sub) scan of partials + scatter.
// cursor ends as START offsets; counts written by sub==0.
// ---------------------------------------------------------------------------
__global__ __launch_bounds__(256) void fillscan_kernel(
        const int* __restrict__ E,
        const int* __restrict__ partial,
        int* __restrict__ counts, int* __restrict__ cursor,
        int* __restrict__ srcIdx) {
    __shared__ int cur[NNODE];
    __shared__ int tsum[256];
    int bid = blockIdx.x;
    int t = threadIdx.x;
    int b = bid & 15, sub = bid >> 4;
    const int* pb = partial + (size_t)b * SUB * NNODE;

    int tot[8] = {}, pre[8] = {};
    for (int k = 0; k < SUB; ++k) {
        const int4* p = reinterpret_cast<const int4*>(pb + k * NNODE + t * 8);
        int4 a = p[0], c = p[1];
        if (k < sub) {
            pre[0] += a.x; pre[1] += a.y; pre[2] += a.z; pre[3] += a.w;
            pre[4] += c.x; pre[5] += c.y; pre[6] += c.z; pre[7] += c.w;
        }
        tot[0] += a.x; tot[1] += a.y; tot[2] += a.z; tot[3] += a.w;
        tot[4] += c.x; tot[5] += c.y; tot[6] += c.z; tot[7] += c.w;
    }
    int s = 0;
#pragma unroll
    for (int j = 0; j < 8; ++j) s += tot[j];
    tsum[t] = s;
    __syncthreads();
    for (int off = 1; off < 256; off <<= 1) {
        int v = (t >= off) ? tsum[t - off] : 0;
        __syncthreads();
        tsum[t] += v;
        __syncthreads();
    }
    int run = (t == 0) ? 0 : tsum[t - 1];
    bool writer = (sub == 0);
    int base = b * NNODE + t * 8;
#pragma unroll
    for (int j = 0; j < 8; ++j) {
        cur[t * 8 + j] = run + pre[j];
        if (writer) { counts[base + j] = tot[j]; cursor[base + j] = run; }
        run += tot[j];
    }
    __syncthreads();

    const int* eb = E + (size_t)b * 2 * NEDGE;
    const int4* srcs = reinterpret_cast<const int4*>(eb + sub * ESUB);
    const int4* dsts = reinterpret_cast<const int4*>(eb + NEDGE + sub * ESUB);
    int* sb = srcIdx + (size_t)b * NEDGE;
#pragma unroll
    for (int j = 0; j < 4; ++j) {
        int4 sv = srcs[j * 256 + t];
        int4 dv = dsts[j * 256 + t];
        sb[atomicAdd(&cur[dv.x], 1)] = sv.x;
        sb[atomicAdd(&cur[dv.y], 1)] = sv.y;
        sb[atomicAdd(&cur[dv.z], 1)] = sv.z;
        sb[atomicAdd(&cur[dv.w], 1)] = sv.w;
    }
}

// ---------------------------------------------------------------------------
// pull-style neighbor mean over int8 features, SWAR packed-u16 accumulate
// (exact), output = fp8 e4m3 written DIRECTLY in the swizzled 128-row panel
// image the GEMM will load linearly into LDS:
//   addr = panel*32768 + (r*16 + (l16 ^ ((r>>1)&7)))*16, word-pair rotated
//   by r&1 (round-13-verified layout). 8192 blocks (full TLP — the round-13
//   fusion lesson), quarter-wave per edge, 16B uint4 gathers.
// ---------------------------------------------------------------------------
__global__ __launch_bounds__(256) void aggregate_kernel(
        const unsigned char* __restrict__ Xi8,
        const int* __restrict__ srcIdx,
        const int* __restrict__ cursor,
        const int* __restrict__ counts,
        unsigned char* __restrict__ Gq) {
    int bid = blockIdx.x;                     // 8192 blocks
    int blk = (bid & 7) * 1024 + (bid >> 3);  // XCD-contiguous remap (bijective)
    int wave = threadIdx.x >> 6;
    int lane = threadIdx.x & 63;
    int q = lane >> 4;                        // edge slot 0..3
    int l16 = lane & 15;                      // feature group
    int f0 = l16 * 16;                        // 16 bytes per lane
    int node = blk * 4 + wave;                // 0 .. B*N-1
    int b = node >> 11;
    int deg = counts[node];
    int start = cursor[node];
    const unsigned char* xb = Xi8 + (size_t)b * NNODE * DIN;
    const int* sidx = srcIdx + (size_t)b * NEDGE + start;

    unsigned a0 = 0, a1 = 0, a2 = 0, a3 = 0, a4 = 0, a5 = 0, a6 = 0, a7 = 0;
#define M16 0x00FF00FFu
#define ACC16(v) do {                                                         \
        unsigned w0 = (v).x ^ 0x80808080u, w1 = (v).y ^ 0x80808080u;          \
        unsigned w2 = (v).z ^ 0x80808080u, w3 = (v).w ^ 0x80808080u;          \
        a0 += w0 & M16;  a1 += (w0 >> 8) & M16;                               \
        a2 += w1 & M16;  a3 += (w1 >> 8) & M16;                               \
        a4 += w2 & M16;  a5 += (w2 >> 8) & M16;                               \
        a6 += w3 & M16;  a7 += (w3 >> 8) & M16;                               \
    } while (0)

    int i = 0;
    for (; i + 16 <= deg; i += 16) {
        int s0 = sidx[i + q], s1 = sidx[i + 4 + q];
        int s2 = sidx[i + 8 + q], s3 = sidx[i + 12 + q];
        uint4 v0 = *reinterpret_cast<const uint4*>(xb + (size_t)s0 * DIN + f0);
        uint4 v1 = *reinterpret_cast<const uint4*>(xb + (size_t)s1 * DIN + f0);
        uint4 v2 = *reinterpret_cast<const uint4*>(xb + (size_t)s2 * DIN + f0);
        uint4 v3 = *reinterpret_cast<const uint4*>(xb + (size_t)s3 * DIN + f0);
        ACC16(v0); ACC16(v1); ACC16(v2); ACC16(v3);
    }
    for (; i < deg; i += 4) {
        int e = i + q;
        uint4 v = { 0x80808080u, 0x80808080u, 0x80808080u, 0x80808080u };
        if (e < deg)
            v = *reinterpret_cast<const uint4*>(xb + (size_t)sidx[e] * DIN + f0);
        ACC16(v);
    }
#undef ACC16
#undef M16
    a0 += (unsigned)__shfl_xor((int)a0, 16, 64); a0 += (unsigned)__shfl_xor((int)a0, 32, 64);
    a1 += (unsigned)__shfl_xor((int)a1, 16, 64); a1 += (unsigned)__shfl_xor((int)a1, 32, 64);
    a2 += (unsigned)__shfl_xor((int)a2, 16, 64); a2 += (unsigned)__shfl_xor((int)a2, 32, 64);
    a3 += (unsigned)__shfl_xor((int)a3, 16, 64); a3 += (unsigned)__shfl_xor((int)a3, 32, 64);
    a4 += (unsigned)__shfl_xor((int)a4, 16, 64); a4 += (unsigned)__shfl_xor((int)a4, 32, 64);
    a5 += (unsigned)__shfl_xor((int)a5, 16, 64); a5 += (unsigned)__shfl_xor((int)a5, 32, 64);
    a6 += (unsigned)__shfl_xor((int)a6, 16, 64); a6 += (unsigned)__shfl_xor((int)a6, 32, 64);
    a7 += (unsigned)__shfl_xor((int)a7, 16, 64); a7 += (unsigned)__shfl_xor((int)a7, 32, 64);

    if (q == 0) {
        float sc = 1.0f / (16.0f * (float)max(deg, 1));
        float bs = 128.0f * (float)deg;
        float f[16];
        f[ 0] = ((float)(int)(a0 & 0xFFFFu) - bs) * sc;
        f[ 2] = ((float)(int)(a0 >> 16)     - bs) * sc;
        f[ 1] = ((float)(int)(a1 & 0xFFFFu) - bs) * sc;
        f[ 3] = ((float)(int)(a1 >> 16)     - bs) * sc;
        f[ 4] = ((float)(int)(a2 & 0xFFFFu) - bs) * sc;
        f[ 6] = ((float)(int)(a2 >> 16)     - bs) * sc;
        f[ 5] = ((float)(int)(a3 & 0xFFFFu) - bs) * sc;
        f[ 7] = ((float)(int)(a3 >> 16)     - bs) * sc;
        f[ 8] = ((float)(int)(a4 & 0xFFFFu) - bs) * sc;
        f[10] = ((float)(int)(a4 >> 16)     - bs) * sc;
        f[ 9] = ((float)(int)(a5 & 0xFFFFu) - bs) * sc;
        f[11] = ((float)(int)(a5 >> 16)     - bs) * sc;
        f[12] = ((float)(int)(a6 & 0xFFFFu) - bs) * sc;
        f[14] = ((float)(int)(a6 >> 16)     - bs) * sc;
        f[13] = ((float)(int)(a7 & 0xFFFFu) - bs) * sc;
        f[15] = ((float)(int)(a7 >> 16)     - bs) * sc;
        unsigned wds[4];
#pragma unroll
        for (int w = 0; w < 4; ++w) {
            unsigned t0 = pk2_fp8<false>(f[4 * w], f[4 * w + 1], 0u);
            wds[w] = pk2_fp8<true>(f[4 * w + 2], f[4 * w + 3], t0);
        }
        int panel = node >> 7, r = node & 127;
        int slot = l16 ^ ((r >> 1) & 7);
        uint4 val;
        if (r & 1) { val.x = wds[2]; val.y = wds[3]; val.z = wds[0]; val.w = wds[1]; }
        else       { val.x = wds[0]; val.y = wds[1]; val.z = wds[2]; val.w = wds[3]; }
        *reinterpret_cast<uint4*>(
            Gq + ((size_t)panel * 2048 + r * 16 + slot) * 16) = val;
    }
}

// ---------------------------------------------------------------------------
// bf16+fp8 MFMA GEMM: 128x128 tile, 512 blocks (2/CU), 256 thr.
// t<8: bf16 K-steps (Xbf/Wbf staged, chunk-XOR swizzle both sides) + one
//      4KB linear chunk of the pre-swizzled Gq panel per step.
// t>=8: fp8 K-steps: A straight from LDS Gq, B = 4KB fp8 W tiles staged
//      double-buffered into the (now dead) low 4KB of Bs[kt&1].
// LDS = 16 + 16 + 32 = 64 KB -> 2 blocks/CU. Counted vmcnt throughout.
// ---------------------------------------------------------------------------
__global__ __launch_bounds__(256) void gemm_kernel(
        const ushort* __restrict__ Xbf,
        const unsigned char* __restrict__ Gq,
        const ushort* __restrict__ Wbf,
        const unsigned char* __restrict__ Wf8s,
        const float* __restrict__ bias,
        float* __restrict__ out) {
    __shared__ ushort As[2][128 * 32];   // 16 KB
    __shared__ ushort Bs[2][128 * 32];   // 16 KB; low 4KB aliased by fp8 W
    __shared__ uint4  GqV[2048];         // 32 KB

    const int tid = threadIdx.x;
    const int wid = tid >> 6, lane = tid & 63;

    int orig = blockIdx.x;
    int logical = (orig & 7) * 64 + (orig >> 3);
    int bx = logical >> 1;
    int by = logical & 1;
    const int rowBase = bx * 128;
    const int colBase = by * 128;
    const int wm = wid >> 1, wn = wid & 1;

    f32x4 acc[4][4] = {};

    const int lk = (((lane & 3) ^ ((lane >> 3) & 3)) * 8);
    const ushort* Arow = Xbf + (size_t)rowBase * DIN;
    const ushort* Brow = Wbf + (size_t)colBase * KDIM;
    const unsigned char* GqPanel = Gq + (size_t)bx * 32768;
    const int r0 = wid * 16 + (lane >> 2);

#define STAGE_X(k0, buf) do {                                                 \
        ASYNC_COPY16(Arow + (size_t)r0 * DIN + (k0) + lk,         &As[buf][wid * 512]);       \
        ASYNC_COPY16(Arow + (size_t)(r0 + 64) * DIN + (k0) + lk,  &As[buf][2048 + wid * 512]);\
        ASYNC_COPY16(Brow + (size_t)r0 * KDIM + (k0) + lk,        &Bs[buf][wid * 512]);       \
        ASYNC_COPY16(Brow + (size_t)(r0 + 64) * KDIM + (k0) + lk, &Bs[buf][2048 + wid * 512]);\
    } while (0)
#define GQ_STAGE(t8) \
        ASYNC_COPY16(GqPanel + (t8) * 4096 + wid * 1024 + lane * 16, \
                     (char*)GqV + (t8) * 4096 + wid * 1024)
#define SG8_STAGE(kt) \
        ASYNC_COPY16(Wf8s + (size_t)(kt) * 8192 + wid * 2048 + ((size_t)colBase + lane * 2) * 8, \
                     (char*)&Bs[(kt) & 1][0] + wid * 1024)

    const int fl = lane & 15;
    const int kq = lane >> 4;
    const int fc = (kq ^ ((fl >> 1) & 3)) * 8;     // bf16 fragment chunk
    const long* GqL = reinterpret_cast<const long*>(GqV);

    STAGE_X(0, 0);
    for (int t = 0; t < 16; ++t) {
        if (t < 7) {
            GQ_STAGE(t);
            STAGE_X((t + 1) * 32, (t + 1) & 1);
            asm volatile("s_waitcnt vmcnt(5)" ::: "memory");   // tile t + GQ(t-1) done
        } else if (t == 7) {
            GQ_STAGE(7);
            SG8_STAGE(0);
            asm volatile("s_waitcnt vmcnt(2)" ::: "memory");   // tile 7 + GQ(6) done
        } else if (t < 15) {
            SG8_STAGE(t - 7);
            asm volatile("s_waitcnt vmcnt(1)" ::: "memory");   // prev fp8 W + GQ(7) done
        } else {
            asm volatile("s_waitcnt vmcnt(0)" ::: "memory");
        }
        __builtin_amdgcn_s_barrier();

        if (t < 8) {
            const int bufx = t & 1;
            short8 a[4], bb[4];
#pragma unroll
            for (int m = 0; m < 4; ++m)
                a[m] = *reinterpret_cast<const short8*>(
                    &As[bufx][(wm * 64 + m * 16 + fl) * 32 + fc]);
#pragma unroll
            for (int n = 0; n < 4; ++n)
                bb[n] = *reinterpret_cast<const short8*>(
                    &Bs[bufx][(wn * 64 + n * 16 + fl) * 32 + fc]);
#pragma unroll
            for (int m = 0; m < 4; ++m)
#pragma unroll
                for (int n = 0; n < 4; ++n)
                    acc[m][n] = __builtin_amdgcn_mfma_f32_16x16x32_bf16(
                        a[m], bb[n], acc[m][n], 0, 0, 0);
        } else {
            const int kt = t - 8;
            const unsigned char* Bf8 =
                reinterpret_cast<const unsigned char*>(&Bs[kt & 1][0]);
            long ag[4], bg[4];
#pragma unroll
            for (int m = 0; m < 4; ++m) {
                int r = wm * 64 + m * 16 + fl;
                ag[m] = GqL[r * 32 + ((kt * 4 + kq) ^ (r & 15))];
            }
#pragma unroll
            for (int n = 0; n < 4; ++n) {
                int c = wn * 64 + n * 16 + fl;       // local col in [0,128)
                bg[n] = *reinterpret_cast<const long*>(Bf8 + kq * 1024 + c * 8);
            }
#pragma unroll
            for (int m = 0; m < 4; ++m)
#pragma unroll
                for (int n = 0; n < 4; ++n)
                    acc[m][n] = __builtin_amdgcn_mfma_f32_16x16x32_fp8_fp8(
                        ag[m], bg[n], acc[m][n], 0, 0, 0);
        }
        __builtin_amdgcn_s_barrier();
    }
#undef STAGE_X
#undef GQ_STAGE
#undef SG8_STAGE

    const int cl = lane & 15, rq = lane >> 4;
#pragma unroll
    for (int n = 0; n < 4; ++n) {
        int col = colBase + wn * 64 + n * 16 + cl;
        float bv = bias[col];
#pragma unroll
        for (int m = 0; m < 4; ++m) {
            int r0o = rowBase + wm * 64 + m * 16 + rq * 4;
#pragma unroll
            for (int j = 0; j < 4; ++j)
                out[(size_t)(r0o + j) * DOUT + col] = acc[m][n][j] + bv;
        }
    }
}

// ---------------------------------------------------------------------------
extern "C" void kernel_launch(void* const* d_in, const int* in_sizes, int n_in,
                              void* d_out, int out_size, void* d_ws, size_t ws_size,
                              hipStream_t stream) {
    const float* X    = (const float*)d_in[0];   // (B, N, DIN)
    const int*   E    = (const int*)d_in[1];     // (B, 2, NEDGE) int32
    const float* W    = (const float*)d_in[2];   // (DOUT, KDIM)
    const float* bias = (const float*)d_in[3];   // (DOUT,)
    float* out = (float*)d_out;                  // (B, N, DOUT)

    char* ws = (char*)d_ws;
    ushort* Xbf  = (ushort*)ws;                                       // 16.78 MB
    unsigned char* Xi8 = (unsigned char*)(Xbf + (size_t)BATCH * NNODE * DIN); // 8.39 MB
    ushort* Wbf  = (ushort*)(Xi8 + (size_t)BATCH * NNODE * DIN);      // 512 KB
    unsigned char* Wf8s = (unsigned char*)(Wbf + (size_t)DOUT * KDIM);// 64 KB
    int* counts  = (int*)(Wf8s + 8 * 8192);                           // 128 KB
    int* cursor  = counts + BATCH * NNODE;                            // 128 KB
    int* srcIdx  = cursor + BATCH * NNODE;                            // 4 MB
    int* partial = srcIdx + (size_t)BATCH * NEDGE;                    // 2 MB
    unsigned char* Gq = (unsigned char*)(partial + (size_t)BATCH * SUB * NNODE); // 8.39 MB

    // partial hists (256) + convert X bf16+i8 (4096) + convert W bf16/fp8 (64)
    prep_kernel<<<4416, 256, 0, stream>>>(X, W, E, partial, Xbf, Xi8, Wbf, Wf8s);

    fillscan_kernel<<<256, 256, 0, stream>>>(E, partial, counts, cursor, srcIdx);

    aggregate_kernel<<<(BATCH * NNODE) / 4, 256, 0, stream>>>(
        Xi8, srcIdx, cursor, counts, Gq);

    dim3 ggrid(512);
    gemm_kernel<<<ggrid, 256, 0, stream>>>(Xbf, Gq, Wbf, Wf8s, bias, out);
}